// Round 1
// baseline (365.625 us; speedup 1.0000x reference)
//
#include <hip/hip_runtime.h>
#include <hip/hip_bf16.h>

// PIPNet interface scorer: out[p] = W2 . relu(W1 . concat(g1[il[p]], g2[ir[p]]) + b1) + b2
// Strategy: fused gather->bf16->LDS tile (128 pairs) -> 32x32x16 bf16 MFMA -> fused
// bias/ReLU/W2-dot epilogue with width-32 shuffle reduce. W1 pre-converted to
// B-fragment-ordered bf16 in d_ws by a tiny pre-kernel (32 KB, L2-resident).

typedef __bf16 bf16x8 __attribute__((ext_vector_type(8)));
typedef float f32x16 __attribute__((ext_vector_type(16)));

__device__ __forceinline__ unsigned f2bf(float f) {
  union { float f; unsigned u; } v;
  v.f = f;
  unsigned u = v.u;
  // round-to-nearest-even f32 -> bf16 (matches hardware cvt; inputs are finite)
  return (u + 0x7fffu + ((u >> 16) & 1u)) >> 16;
}

// Pre-kernel: W1 [128x128] f32 row-major -> bf16 B-fragments for
// v_mfma_f32_32x32x16_bf16, stored so the main loop's load is
// uniform_base + lane*16 (perfectly coalesced, 32 KB total).
// Fragment (ks, nt, lane): n = lane&31, h = lane>>5;
//   elements = W1[nt*32+n][ks*16 + h*8 + j], j = 0..7
__global__ __launch_bounds__(256) void w1_frag_kernel(
    const float* __restrict__ W1, uint4* __restrict__ w1f) {
  int t = blockIdx.x * 256 + threadIdx.x;  // 0..2047
  int lane = t & 63;
  int nt = (t >> 6) & 3;
  int ks = t >> 8;
  int n = lane & 31, h = lane >> 5;
  const float4* src =
      (const float4*)(W1 + ((nt * 32 + n) * 128 + ks * 16 + h * 8));
  float4 a = src[0], b = src[1];
  uint4 o;
  o.x = f2bf(a.x) | (f2bf(a.y) << 16);
  o.y = f2bf(a.z) | (f2bf(a.w) << 16);
  o.z = f2bf(b.x) | (f2bf(b.y) << 16);
  o.w = f2bf(b.z) | (f2bf(b.w) << 16);
  w1f[t] = o;
}

#define LDS_STRIDE 136  // 128 + 8 bf16 pad: breaks 256B-stride bank aliasing

__global__ __launch_bounds__(256, 4) void pip_main_kernel(
    const float* __restrict__ g1, const float* __restrict__ g2,
    const int* __restrict__ il, const int* __restrict__ ir,
    const bf16x8* __restrict__ w1f,
    const float* __restrict__ b1, const float* __restrict__ w2,
    const float* __restrict__ b2,
    float* __restrict__ out, int P) {
  __shared__ unsigned short A[128 * LDS_STRIDE];  // 34,816 B -> 4 blocks/CU

  const int t = threadIdx.x;
  const int pair0 = blockIdx.x * 128;

  // ---- Stage: gather 128 pairs x (left 64f + right 64f) as bf16 into LDS ----
  // 512 jobs = (pair, side, half-of-64-floats); 2 passes over 256 threads.
  // Each job: 8 float4 loads (128 B contiguous) -> 32 bf16 -> 4 uint4 LDS writes.
#pragma unroll
  for (int pass = 0; pass < 2; ++pass) {
    int j2 = pass * 256 + t;
    int lp = j2 >> 2;
    int side = (j2 >> 1) & 1;
    int half = j2 & 1;
    int gp = pair0 + lp;
    int pidx = (gp < P) ? gp : (P - 1);
    int idx = side ? ir[pidx] : il[pidx];
    const float* feat = side ? g2 : g1;
    const float4* src = (const float4*)(feat + (size_t)idx * 64 + half * 32);
    float4 v[8];
#pragma unroll
    for (int i = 0; i < 8; ++i) v[i] = src[i];
    unsigned pk[16];
#pragma unroll
    for (int i = 0; i < 8; ++i) {
      pk[2 * i]     = f2bf(v[i].x) | (f2bf(v[i].y) << 16);
      pk[2 * i + 1] = f2bf(v[i].z) | (f2bf(v[i].w) << 16);
    }
    uint4* dst = (uint4*)(A + lp * LDS_STRIDE + side * 64 + half * 32);
#pragma unroll
    for (int i = 0; i < 4; ++i)
      dst[i] = make_uint4(pk[4 * i], pk[4 * i + 1], pk[4 * i + 2], pk[4 * i + 3]);
  }
  __syncthreads();

  // ---- Compute: wave w handles pairs [w*32, w*32+32), full n = 0..127 ----
  const int lane = t & 63;
  const int w = t >> 6;
  const int n = lane & 31;   // MFMA n-index (and A-row m-index) within tile
  const int h = lane >> 5;   // lane half -> k-block / row offset

  f32x16 acc[4];
#pragma unroll
  for (int nt = 0; nt < 4; ++nt)
#pragma unroll
    for (int i = 0; i < 16; ++i) acc[nt][i] = 0.0f;

  const unsigned short* Arow = A + (w * 32 + n) * LDS_STRIDE + h * 8;
#pragma unroll
  for (int ks = 0; ks < 8; ++ks) {
    bf16x8 af = *(const bf16x8*)(Arow + ks * 16);
#pragma unroll
    for (int nt = 0; nt < 4; ++nt) {
      bf16x8 bfr = w1f[(ks * 4 + nt) * 64 + lane];
      acc[nt] = __builtin_amdgcn_mfma_f32_32x32x16_bf16(af, bfr, acc[nt], 0, 0, 0);
    }
  }

  // ---- Epilogue: out[p] = sum_n relu(acc + b1[n]) * w2[n] + b2 ----
  // C/D layout: col(n) = lane&31 (+32*nt), row(m) = (r&3) + 8*(r>>2) + 4*h.
  float b1v[4], w2v[4];
#pragma unroll
  for (int nt = 0; nt < 4; ++nt) {
    b1v[nt] = b1[nt * 32 + n];
    w2v[nt] = w2[nt * 32 + n];
  }
  const float bias2 = b2[0];

#pragma unroll
  for (int r = 0; r < 16; ++r) {
    float s = 0.0f;
#pragma unroll
    for (int nt = 0; nt < 4; ++nt) {
      float v = acc[nt][r] + b1v[nt];
      v = fmaxf(v, 0.0f);
      s = fmaf(v, w2v[nt], s);
    }
    // reduce over the 32 lanes of this half (n covers 0..31)
    s += __shfl_xor(s, 1);
    s += __shfl_xor(s, 2);
    s += __shfl_xor(s, 4);
    s += __shfl_xor(s, 8);
    s += __shfl_xor(s, 16);
    if (n == 0) {
      int row = (r & 3) + 8 * (r >> 2) + 4 * h;
      int gp = pair0 + w * 32 + row;
      if (gp < P) out[gp] = s + bias2;
    }
  }
}

extern "C" void kernel_launch(void* const* d_in, const int* in_sizes, int n_in,
                              void* d_out, int out_size, void* d_ws, size_t ws_size,
                              hipStream_t stream) {
  const float* g1 = (const float*)d_in[0];   // graph1_x [N,64] f32
  const float* g2 = (const float*)d_in[1];   // graph2_x [N,64] f32
  const int* il = (const int*)d_in[2];       // idx_left [P] (int32 on device; jax x64 off)
  const int* ir = (const int*)d_in[3];       // idx_right [P]
  const float* W1 = (const float*)d_in[4];   // [128,128]
  const float* b1 = (const float*)d_in[5];   // [128]
  const float* w2 = (const float*)d_in[6];   // [1,128]
  const float* b2 = (const float*)d_in[7];   // [1]
  float* out = (float*)d_out;                // [P,1] f32
  const int P = out_size;

  // d_ws: 32 KB of bf16 W1 B-fragments (rebuilt every call; ws is re-poisoned)
  w1_frag_kernel<<<8, 256, 0, stream>>>(W1, (uint4*)d_ws);

  const int nblocks = (P + 127) / 128;
  pip_main_kernel<<<nblocks, 256, 0, stream>>>(
      g1, g2, il, ir, (const bf16x8*)d_ws, b1, w2, b2, out, P);
}

// Round 2
// 335.226 us; speedup vs baseline: 1.0907x; 1.0907x over previous
//
#include <hip/hip_runtime.h>
#include <hip/hip_bf16.h>

// PIPNet interface scorer: out[p] = W2 . relu(W1 . concat(g1[il[p]], g2[ir[p]]) + b1) + b2
// R2: coalesced cooperative gather — 16 lanes per 256B feature row (was: 1 lane
// per 128B half-row => 64-way VMEM cracking, issue-bound at 1.45 TB/s).

typedef __bf16 bf16x8 __attribute__((ext_vector_type(8)));
typedef float f32x16 __attribute__((ext_vector_type(16)));

__device__ __forceinline__ unsigned f2bf(float f) {
  union { float f; unsigned u; } v;
  v.f = f;
  unsigned u = v.u;
  // round-to-nearest-even f32 -> bf16
  return (u + 0x7fffu + ((u >> 16) & 1u)) >> 16;
}

// Pre-kernel: W1 [128x128] f32 row-major -> bf16 B-fragments for
// v_mfma_f32_32x32x16_bf16; main-loop load is uniform_base + lane*16.
// Fragment (ks, nt, lane): n = lane&31, h = lane>>5;
//   elements = W1[nt*32+n][ks*16 + h*8 + j], j = 0..7
__global__ __launch_bounds__(256) void w1_frag_kernel(
    const float* __restrict__ W1, uint4* __restrict__ w1f) {
  int t = blockIdx.x * 256 + threadIdx.x;  // 0..2047
  int lane = t & 63;
  int nt = (t >> 6) & 3;
  int ks = t >> 8;
  int n = lane & 31, h = lane >> 5;
  const float4* src =
      (const float4*)(W1 + ((nt * 32 + n) * 128 + ks * 16 + h * 8));
  float4 a = src[0], b = src[1];
  uint4 o;
  o.x = f2bf(a.x) | (f2bf(a.y) << 16);
  o.y = f2bf(a.z) | (f2bf(a.w) << 16);
  o.z = f2bf(b.x) | (f2bf(b.y) << 16);
  o.w = f2bf(b.z) | (f2bf(b.w) << 16);
  w1f[t] = o;
}

#define LDS_STRIDE 136  // shorts; 272B rows, 16B-aligned for ds_read_b128

__global__ __launch_bounds__(256, 4) void pip_main_kernel(
    const float* __restrict__ g1, const float* __restrict__ g2,
    const int* __restrict__ il, const int* __restrict__ ir,
    const bf16x8* __restrict__ w1f,
    const float* __restrict__ b1, const float* __restrict__ w2,
    const float* __restrict__ b2,
    float* __restrict__ out, int P) {
  __shared__ unsigned short A[128 * LDS_STRIDE];  // 34,816 B -> 4 blocks/CU

  const int t = threadIdx.x;
  const int lane = t & 63;
  const int w = t >> 6;
  const int pair0 = blockIdx.x * 128;

  // ---- Cooperative gather: 16 lanes per (pair,side) row of 64 floats ----
  // Round j covers rows r = j*16 + w*4 + g, g = lane>>4. Since rounds step by
  // 16 (even), side = r&1 = g&1 is FIXED per thread; pair = j*8 + (w*4+g)>>1.
  const int sub = lane & 15;          // lane's 16B slice within the row
  const int g = lane >> 4;
  const int side = g & 1;             // 0: left/g1, 1: right/g2
  const int pairB = (w * 4 + g) >> 1; // 0..7
  const float* feat = side ? g2 : g1;
  const int* idxarr = side ? ir : il;

  int idxv[16];
#pragma unroll
  for (int j = 0; j < 16; ++j) {
    int gp = pair0 + j * 8 + pairB;
    int pidx = (gp < P) ? gp : (P - 1);
    idxv[j] = idxarr[pidx];
  }
#pragma unroll
  for (int j = 0; j < 16; ++j) {
    int pair = j * 8 + pairB;
    // 16 consecutive lanes read 256B contiguous => ~2 granules per row
    float4 v = *(const float4*)(feat + (size_t)idxv[j] * 64 + sub * 4);
    unsigned lo = f2bf(v.x) | (f2bf(v.y) << 16);
    unsigned hi = f2bf(v.z) | (f2bf(v.w) << 16);
    *(uint2*)(A + pair * LDS_STRIDE + side * 64 + sub * 4) =
        make_uint2(lo, hi);
  }
  __syncthreads();

  // ---- Compute: wave w handles pairs [w*32, w*32+32), full n = 0..127 ----
  const int n = lane & 31;   // MFMA m/n index within tile
  const int h = lane >> 5;   // k-block / row offset half

  f32x16 acc[4];
#pragma unroll
  for (int nt = 0; nt < 4; ++nt)
#pragma unroll
    for (int i = 0; i < 16; ++i) acc[nt][i] = 0.0f;

  const unsigned short* Arow = A + (w * 32 + n) * LDS_STRIDE + h * 8;
#pragma unroll
  for (int ks = 0; ks < 8; ++ks) {
    bf16x8 af = *(const bf16x8*)(Arow + ks * 16);
#pragma unroll
    for (int nt = 0; nt < 4; ++nt) {
      bf16x8 bfr = w1f[(ks * 4 + nt) * 64 + lane];
      acc[nt] = __builtin_amdgcn_mfma_f32_32x32x16_bf16(af, bfr, acc[nt], 0, 0, 0);
    }
  }

  // ---- Epilogue: out[p] = sum_n relu(acc + b1[n]) * w2[n] + b2 ----
  // C/D layout: col(n) = lane&31 (+32*nt), row(m) = (r&3) + 8*(r>>2) + 4*h.
  float b1v[4], w2v[4];
#pragma unroll
  for (int nt = 0; nt < 4; ++nt) {
    b1v[nt] = b1[nt * 32 + n];
    w2v[nt] = w2[nt * 32 + n];
  }
  const float bias2 = b2[0];

#pragma unroll
  for (int r = 0; r < 16; ++r) {
    float s = 0.0f;
#pragma unroll
    for (int nt = 0; nt < 4; ++nt) {
      float v = acc[nt][r] + b1v[nt];
      v = fmaxf(v, 0.0f);
      s = fmaf(v, w2v[nt], s);
    }
    s += __shfl_xor(s, 1);
    s += __shfl_xor(s, 2);
    s += __shfl_xor(s, 4);
    s += __shfl_xor(s, 8);
    s += __shfl_xor(s, 16);
    if (n == 0) {
      int row = (r & 3) + 8 * (r >> 2) + 4 * h;
      int gp = pair0 + w * 32 + row;
      if (gp < P) out[gp] = s + bias2;
    }
  }
}

extern "C" void kernel_launch(void* const* d_in, const int* in_sizes, int n_in,
                              void* d_out, int out_size, void* d_ws, size_t ws_size,
                              hipStream_t stream) {
  const float* g1 = (const float*)d_in[0];   // graph1_x [N,64] f32
  const float* g2 = (const float*)d_in[1];   // graph2_x [N,64] f32
  const int* il = (const int*)d_in[2];       // idx_left [P] int32
  const int* ir = (const int*)d_in[3];       // idx_right [P] int32
  const float* W1 = (const float*)d_in[4];   // [128,128]
  const float* b1 = (const float*)d_in[5];   // [128]
  const float* w2 = (const float*)d_in[6];   // [1,128]
  const float* b2 = (const float*)d_in[7];   // [1]
  float* out = (float*)d_out;                // [P,1] f32
  const int P = out_size;

  // d_ws: 32 KB of bf16 W1 B-fragments (rebuilt every call; ws is re-poisoned)
  w1_frag_kernel<<<8, 256, 0, stream>>>(W1, (uint4*)d_ws);

  const int nblocks = (P + 127) / 128;
  pip_main_kernel<<<nblocks, 256, 0, stream>>>(
      g1, g2, il, ir, (const bf16x8*)d_ws, b1, w2, b2, out, P);
}